// Round 3
// baseline (918.067 us; speedup 1.0000x reference)
//
#include <hip/hip_runtime.h>

// Problem constants
#define N_NODES 100000
#define N_EDGES 1600000
#define HDIM    64
#define NGRAPH  64
#define BLK_NODES 8
#define ALPHA_C 0.5f
#define BETA_C  0.5f

// ---------------------------------------------------------------- histogram
__global__ __launch_bounds__(256) void hist_kernel(const int* __restrict__ ei,
                                                   int* __restrict__ deg_out,
                                                   int* __restrict__ deg_in) {
    int e = blockIdx.x * 256 + threadIdx.x;
    if (e < N_EDGES) {
        int r = ei[e];
        int c = ei[N_EDGES + e];
        atomicAdd(&deg_out[r], 1);
        atomicAdd(&deg_in[c], 1);
    }
}

// ------------------------------------------------------------------- rsqrt
__global__ __launch_bounds__(256) void rsq_kernel(const int* __restrict__ deg_out,
                                                  const int* __restrict__ deg_in,
                                                  float* __restrict__ r_out,
                                                  float* __restrict__ r_in) {
    int i = blockIdx.x * 256 + threadIdx.x;
    if (i < N_NODES) {
        int d0 = deg_out[i];
        int d1 = deg_in[i];
        r_out[i] = d0 > 0 ? 1.0f / sqrtf((float)d0) : 0.0f;
        r_in[i]  = d1 > 0 ? 1.0f / sqrtf((float)d1) : 0.0f;
    }
}

// ----------------------------------------------------- block-level exclusive scan
__global__ __launch_bounds__(1024) void scan_block(const int* __restrict__ deg0,
                                                   const int* __restrict__ deg1,
                                                   int* __restrict__ out0,
                                                   int* __restrict__ out1,
                                                   int* __restrict__ bsum0,
                                                   int* __restrict__ bsum1) {
    const int* deg = blockIdx.y ? deg1 : deg0;
    int* out  = blockIdx.y ? out1  : out0;
    int* bsum = blockIdx.y ? bsum1 : bsum0;

    __shared__ int s[1024];
    int tid = threadIdx.x;
    int i = blockIdx.x * 1024 + tid;
    int v = (i < N_NODES) ? deg[i] : 0;
    s[tid] = v;
    __syncthreads();
    for (int off = 1; off < 1024; off <<= 1) {
        int t = (tid >= off) ? s[tid - off] : 0;
        __syncthreads();
        s[tid] += t;
        __syncthreads();
    }
    if (i < N_NODES) out[i] = s[tid] - v;   // exclusive within block
    if (tid == 1023) bsum[blockIdx.x] = s[1023];
}

__global__ __launch_bounds__(128) void scan_bsums(int* __restrict__ bsum0,
                                                  int* __restrict__ bsum1,
                                                  int nb) {
    int* b = blockIdx.x ? bsum1 : bsum0;
    __shared__ int s[128];
    int tid = threadIdx.x;
    int v = (tid < nb) ? b[tid] : 0;
    s[tid] = v;
    __syncthreads();
    for (int off = 1; off < 128; off <<= 1) {
        int t = (tid >= off) ? s[tid - off] : 0;
        __syncthreads();
        s[tid] += t;
        __syncthreads();
    }
    if (tid < nb) b[tid] = s[tid] - v;      // exclusive
}

__global__ __launch_bounds__(256) void scan_add(int* __restrict__ out0,
                                                int* __restrict__ out1,
                                                const int* __restrict__ bsum0,
                                                const int* __restrict__ bsum1,
                                                int* __restrict__ cur0,
                                                int* __restrict__ cur1) {
    int i = blockIdx.x * 256 + threadIdx.x;
    if (i < N_NODES) {
        if (blockIdx.y == 0) {
            int v = out0[i] + bsum0[i >> 10];
            out0[i] = v;
            cur0[i] = v;
        } else {
            int v = out1[i] + bsum1[i >> 10];
            out1[i] = v;
            cur1[i] = v;
        }
    }
}

// --------------------------------------------------------- counting-sort scatter
// index-only records (4B): norm weights are recomputed in the layer kernel
__global__ __launch_bounds__(256) void scatter_kernel(const int* __restrict__ ei,
                                                      int* __restrict__ cur_row,
                                                      int* __restrict__ cur_col,
                                                      int* __restrict__ idxA,
                                                      int* __restrict__ idxT) {
    int e = blockIdx.x * 256 + threadIdx.x;
    if (e < N_EDGES) {
        int r = ei[e];
        int c = ei[N_EDGES + e];
        int p = atomicAdd(&cur_row[r], 1);
        idxA[p] = c;
        int pt = atomicAdd(&cur_col[c], 1);
        idxT[pt] = r;
    }
}

// -------------------------------------------------------------- fused layer
__device__ __forceinline__ void fma4(float4& a, float w, const float4& f) {
    a.x = fmaf(w, f.x, a.x); a.y = fmaf(w, f.y, a.y);
    a.z = fmaf(w, f.z, a.z); a.w = fmaf(w, f.w, a.w);
}

__device__ __forceinline__ float4 red_s(float4 v) {
    v.x += __shfl_xor(v.x, 16); v.y += __shfl_xor(v.y, 16);
    v.z += __shfl_xor(v.z, 16); v.w += __shfl_xor(v.w, 16);
    v.x += __shfl_xor(v.x, 32); v.y += __shfl_xor(v.y, 32);
    v.z += __shfl_xor(v.z, 32); v.w += __shfl_xor(v.w, 32);
    return v;
}

// per-wave aggregation over one direction; lane (q,s): q=feat quad, s=edge slot
// rw[] = per-neighbor scale (r_in for dir A, r_out for dir T)
__device__ __forceinline__ float4 agg_dir(const float4* __restrict__ hv,
                                          const int* __restrict__ idx,
                                          const float* __restrict__ rw,
                                          int start, int deg, int q, int s) {
    float4 a0 = {0.f,0.f,0.f,0.f}, a1 = {0.f,0.f,0.f,0.f};
    int k = 0;
    for (; k + 8 <= deg; k += 8) {
        int c0 = idx[start + k + s];
        int c1 = idx[start + k + 4 + s];
        float w0 = rw[c0];
        float w1 = rw[c1];
        float4 f0 = hv[(size_t)c0 * 16 + q];
        float4 f1 = hv[(size_t)c1 * 16 + q];
        fma4(a0, w0, f0);
        fma4(a1, w1, f1);
    }
    if (k + s < deg) {
        int c0 = idx[start + k + s];
        float4 f0 = hv[(size_t)c0 * 16 + q];
        fma4(a0, rw[c0], f0);
    }
    if (k + 4 + s < deg) {
        int c1 = idx[start + k + 4 + s];
        float4 f1 = hv[(size_t)c1 * 16 + q];
        fma4(a1, rw[c1], f1);
    }
    a0.x += a1.x; a0.y += a1.y; a0.z += a1.z; a0.w += a1.w;
    return red_s(a0);
}

__global__ __launch_bounds__(512, 8) void layer_kernel(
        const float* __restrict__ h_in, float* __restrict__ h_out,
        const int* __restrict__ rowptr, const int* __restrict__ deg_out,
        const int* __restrict__ idxA,
        const int* __restrict__ colptr, const int* __restrict__ deg_in,
        const int* __restrict__ idxT,
        const float* __restrict__ r_out, const float* __restrict__ r_in,
        const float* __restrict__ ws, const float* __restrict__ bs,
        const float* __restrict__ wd, const float* __restrict__ bd) {
    __shared__ float4 s_ws[HDIM * 16];                 // [k][q] 16KB
    __shared__ float4 s_wd[HDIM * 16];                 // 16KB
    __shared__ float4 s_accv[BLK_NODES][2][16];        // 4KB

    const int tid  = threadIdx.x;
    const int wave = tid >> 6;
    const int lane = tid & 63;
    const int q = lane & 15;
    const int s = lane >> 4;
    const int node = blockIdx.x * BLK_NODES + wave;

    // stage weights (1024 float4 each; 512 threads x 2)
    const float4* wsv = (const float4*)ws;
    const float4* wdv = (const float4*)wd;
    s_ws[tid] = wsv[tid]; s_ws[tid + 512] = wsv[tid + 512];
    s_wd[tid] = wdv[tid]; s_wd[tid + 512] = wdv[tid + 512];

    const float4* hv = (const float4*)h_in;

    // dir A: r_out[node] * sum_{c in out-nbrs} r_in[c] * h[c]
    float scaleA = r_out[node];
    float4 aA = agg_dir(hv, idxA, r_in, rowptr[node], deg_out[node], q, s);
    if (s == 0) {
        aA.x *= scaleA; aA.y *= scaleA; aA.z *= scaleA; aA.w *= scaleA;
        s_accv[wave][0][q] = aA;
    }
    // dir T: r_in[node] * sum_{r in in-nbrs} r_out[r] * h[r]
    float scaleT = r_in[node];
    float4 aT = agg_dir(hv, idxT, r_out, colptr[node], deg_in[node], q, s);
    if (s == 0) {
        aT.x *= scaleT; aT.y *= scaleT; aT.z *= scaleT; aT.w *= scaleT;
        s_accv[wave][1][q] = aT;
    }

    __syncthreads();

    // GEMM epilogue: thread -> feats 4q..4q+3 of its node, k in [16s, 16s+16)
    const float* accA = (const float*)&s_accv[wave][0][0];
    const float* accT = (const float*)&s_accv[wave][1][0];
    float4 oA = {0.f,0.f,0.f,0.f}, oT = {0.f,0.f,0.f,0.f};
    const int k0 = s * 16;
#pragma unroll
    for (int i = 0; i < 16; i++) {
        int k = k0 + i;
        float vA = accA[k];
        float vT = accT[k];
        float4 wA = s_ws[k * 16 + q];
        float4 wT = s_wd[k * 16 + q];
        fma4(oA, vA, wA);
        fma4(oT, vT, wT);
    }
    float4 o;
    o.x = ALPHA_C * oA.x + BETA_C * oT.x;
    o.y = ALPHA_C * oA.y + BETA_C * oT.y;
    o.z = ALPHA_C * oA.z + BETA_C * oT.z;
    o.w = ALPHA_C * oA.w + BETA_C * oT.w;
    o = red_s(o);
    if (s == 0) {
        float4 bA = ((const float4*)bs)[q];
        float4 bD = ((const float4*)bd)[q];
        o.x = fmaxf(o.x + ALPHA_C * bA.x + BETA_C * bD.x, 0.0f);
        o.y = fmaxf(o.y + ALPHA_C * bA.y + BETA_C * bD.y, 0.0f);
        o.z = fmaxf(o.z + ALPHA_C * bA.z + BETA_C * bD.z, 0.0f);
        o.w = fmaxf(o.w + ALPHA_C * bA.w + BETA_C * bD.w, 0.0f);
        ((float4*)h_out)[(size_t)node * 16 + q] = o;
    }
}

// ---------------------------------------------------------------- max pool
__global__ __launch_bounds__(256) void pool_kernel(const float* __restrict__ h,
                                                   const int* __restrict__ batch,
                                                   unsigned* __restrict__ g) {
    int t = blockIdx.x * 256 + threadIdx.x;
    const int ngroups = N_NODES / 16;   // 6250
    if (t >= ngroups * 64) return;
    int f = t & 63;
    int n0 = (t >> 6) * 16;
    int curg = batch[n0];
    float m = 0.0f;                      // post-ReLU values are >= 0
    for (int n = n0; n < n0 + 16; n++) {
        int b = batch[n];
        if (b != curg) {
            atomicMax(&g[curg * HDIM + f], __float_as_uint(m));
            curg = b;
            m = 0.0f;
        }
        m = fmaxf(m, h[n * HDIM + f]);
    }
    atomicMax(&g[curg * HDIM + f], __float_as_uint(m));
}

// -------------------------------------------------------------------- MLP head
__global__ __launch_bounds__(64) void mlp_kernel(const unsigned* __restrict__ g,
                                                 const float* __restrict__ wl1,
                                                 const float* __restrict__ bl1,
                                                 const float* __restrict__ wl2,
                                                 const float* __restrict__ bl2,
                                                 float* __restrict__ out) {
    int t = threadIdx.x;   // graph index, one block of 64
    float gv[HDIM];
#pragma unroll
    for (int k = 0; k < HDIM; k++) gv[k] = __uint_as_float(g[t * HDIM + k]);
    float o = bl2[0];
#pragma unroll
    for (int j = 0; j < 5; j++) {
        float hj = bl1[j];
#pragma unroll
        for (int k = 0; k < HDIM; k++) hj += gv[k] * wl1[k * 5 + j];
        hj = fmaxf(hj, 0.0f);
        o += hj * wl2[j];
    }
    out[t] = o;
}

// ------------------------------------------------------------------- launch
extern "C" void kernel_launch(void* const* d_in, const int* in_sizes, int n_in,
                              void* d_out, int out_size, void* d_ws, size_t ws_size,
                              hipStream_t stream) {
    const float* x   = (const float*)d_in[0];
    const int*   ei  = (const int*)d_in[1];
    const int*   bat = (const int*)d_in[2];
    const float* w1s = (const float*)d_in[3];
    const float* b1s = (const float*)d_in[4];
    const float* w1d = (const float*)d_in[5];
    const float* b1d = (const float*)d_in[6];
    const float* w2s = (const float*)d_in[7];
    const float* b2s = (const float*)d_in[8];
    const float* w2d = (const float*)d_in[9];
    const float* b2d = (const float*)d_in[10];
    const float* w3s = (const float*)d_in[11];
    const float* b3s = (const float*)d_in[12];
    const float* w3d = (const float*)d_in[13];
    const float* b3d = (const float*)d_in[14];
    const float* wl1 = (const float*)d_in[15];
    const float* bl1 = (const float*)d_in[16];
    const float* wl2 = (const float*)d_in[17];
    const float* bl2 = (const float*)d_in[18];
    float* out = (float*)d_out;

    // Workspace carve-up (all chunks 16B-aligned)
    char* p = (char*)d_ws;
    int*   deg_out = (int*)p;              p += N_NODES * 4;
    int*   deg_in  = (int*)p;              p += N_NODES * 4;
    int*   rowptr  = (int*)p;              p += N_NODES * 4;
    int*   colptr  = (int*)p;              p += N_NODES * 4;
    int*   cur_row = (int*)p;              p += N_NODES * 4;
    int*   cur_col = (int*)p;              p += N_NODES * 4;
    float* r_out   = (float*)p;            p += N_NODES * 4;
    float* r_in    = (float*)p;            p += N_NODES * 4;
    int*   idxA    = (int*)p;              p += (size_t)N_EDGES * 4;
    int*   idxT    = (int*)p;              p += (size_t)N_EDGES * 4;
    float* hA      = (float*)p;            p += (size_t)N_NODES * HDIM * 4;
    float* hB      = (float*)p;            p += (size_t)N_NODES * HDIM * 4;
    unsigned* g    = (unsigned*)p;         p += NGRAPH * HDIM * 4;
    int*   bsum0   = (int*)p;              p += 512;
    int*   bsum1   = (int*)p;              p += 512;

    const int nb = (N_NODES + 1023) / 1024;   // 98 scan blocks

    hipMemsetAsync(deg_out, 0, 2 * N_NODES * 4, stream);
    hipMemsetAsync(g, 0, NGRAPH * HDIM * 4, stream);

    hist_kernel<<<(N_EDGES + 255) / 256, 256, 0, stream>>>(ei, deg_out, deg_in);
    rsq_kernel<<<(N_NODES + 255) / 256, 256, 0, stream>>>(deg_out, deg_in, r_out, r_in);

    dim3 gs(nb, 2);
    scan_block<<<gs, 1024, 0, stream>>>(deg_out, deg_in, rowptr, colptr, bsum0, bsum1);
    scan_bsums<<<2, 128, 0, stream>>>(bsum0, bsum1, nb);
    dim3 ga((N_NODES + 255) / 256, 2);
    scan_add<<<ga, 256, 0, stream>>>(rowptr, colptr, bsum0, bsum1, cur_row, cur_col);

    scatter_kernel<<<(N_EDGES + 255) / 256, 256, 0, stream>>>(
        ei, cur_row, cur_col, idxA, idxT);

    // Three fused conv layers: x -> hA -> hB -> hA
    layer_kernel<<<N_NODES / BLK_NODES, 512, 0, stream>>>(
        x, hA, rowptr, deg_out, idxA, colptr, deg_in, idxT, r_out, r_in,
        w1s, b1s, w1d, b1d);
    layer_kernel<<<N_NODES / BLK_NODES, 512, 0, stream>>>(
        hA, hB, rowptr, deg_out, idxA, colptr, deg_in, idxT, r_out, r_in,
        w2s, b2s, w2d, b2d);
    layer_kernel<<<N_NODES / BLK_NODES, 512, 0, stream>>>(
        hB, hA, rowptr, deg_out, idxA, colptr, deg_in, idxT, r_out, r_in,
        w3s, b3s, w3d, b3d);

    const int pool_threads = (N_NODES / 16) * 64;   // 400000
    pool_kernel<<<(pool_threads + 255) / 256, 256, 0, stream>>>(hA, bat, g);

    mlp_kernel<<<1, 64, 0, stream>>>(g, wl1, bl1, wl2, bl2, out);
}

// Round 4
// 694.306 us; speedup vs baseline: 1.3223x; 1.3223x over previous
//
#include <hip/hip_runtime.h>

// Problem constants
#define N_NODES 100000
#define N_EDGES 1600000
#define HDIM    64
#define NGRAPH  64
#define BLK_NODES 8
#define ALPHA_C 0.5f
#define BETA_C  0.5f
#define BW      256                      // bucket width (nodes); shift = 8
#define NB      391                      // ceil(N_NODES / BW)

// ---------------------------------------------------------------- histogram
__global__ __launch_bounds__(256) void hist_kernel(const int* __restrict__ ei,
                                                   int* __restrict__ deg_out,
                                                   int* __restrict__ deg_in) {
    int e = blockIdx.x * 256 + threadIdx.x;
    if (e < N_EDGES) {
        int r = ei[e];
        int c = ei[N_EDGES + e];
        atomicAdd(&deg_out[r], 1);
        atomicAdd(&deg_in[c], 1);
    }
}

// ------------------------------------------------------------------- rsqrt
__global__ __launch_bounds__(256) void rsq_kernel(const int* __restrict__ deg_out,
                                                  const int* __restrict__ deg_in,
                                                  float* __restrict__ r_out,
                                                  float* __restrict__ r_in) {
    int i = blockIdx.x * 256 + threadIdx.x;
    if (i < N_NODES) {
        int d0 = deg_out[i];
        int d1 = deg_in[i];
        r_out[i] = d0 > 0 ? 1.0f / sqrtf((float)d0) : 0.0f;
        r_in[i]  = d1 > 0 ? 1.0f / sqrtf((float)d1) : 0.0f;
    }
}

// ----------------------------------------------------- block-level exclusive scan
__global__ __launch_bounds__(1024) void scan_block(const int* __restrict__ deg0,
                                                   const int* __restrict__ deg1,
                                                   int* __restrict__ out0,
                                                   int* __restrict__ out1,
                                                   int* __restrict__ bsum0,
                                                   int* __restrict__ bsum1) {
    const int* deg = blockIdx.y ? deg1 : deg0;
    int* out  = blockIdx.y ? out1  : out0;
    int* bsum = blockIdx.y ? bsum1 : bsum0;

    __shared__ int s[1024];
    int tid = threadIdx.x;
    int i = blockIdx.x * 1024 + tid;
    int v = (i < N_NODES) ? deg[i] : 0;
    s[tid] = v;
    __syncthreads();
    for (int off = 1; off < 1024; off <<= 1) {
        int t = (tid >= off) ? s[tid - off] : 0;
        __syncthreads();
        s[tid] += t;
        __syncthreads();
    }
    if (i < N_NODES) out[i] = s[tid] - v;   // exclusive within block
    if (tid == 1023) bsum[blockIdx.x] = s[1023];
}

__global__ __launch_bounds__(128) void scan_bsums(int* __restrict__ bsum0,
                                                  int* __restrict__ bsum1,
                                                  int nb) {
    int* b = blockIdx.x ? bsum1 : bsum0;
    __shared__ int s[128];
    int tid = threadIdx.x;
    int v = (tid < nb) ? b[tid] : 0;
    s[tid] = v;
    __syncthreads();
    for (int off = 1; off < 128; off <<= 1) {
        int t = (tid >= off) ? s[tid - off] : 0;
        __syncthreads();
        s[tid] += t;
        __syncthreads();
    }
    if (tid < nb) b[tid] = s[tid] - v;      // exclusive
}

__global__ __launch_bounds__(256) void scan_add(int* __restrict__ out0,
                                                int* __restrict__ out1,
                                                const int* __restrict__ bsum0,
                                                const int* __restrict__ bsum1) {
    int i = blockIdx.x * 256 + threadIdx.x;
    if (i < N_NODES) {
        if (blockIdx.y == 0) out0[i] += bsum0[i >> 10];
        else                 out1[i] += bsum1[i >> 10];
    }
}

// ------------------------------------------- bucket cursor init (chunk allocators)
__global__ __launch_bounds__(512) void init_cursors(const int* __restrict__ rowptr,
                                                    const int* __restrict__ colptr,
                                                    int* __restrict__ curA,
                                                    int* __restrict__ curT) {
    int b = threadIdx.x;
    if (b < NB) {
        curA[b] = rowptr[b * BW];
        curT[b] = colptr[b * BW];
    }
}

// --------------------------------------------------- phase 1: bucketize edges
// Each block processes a contiguous edge slice; per-bucket LDS histogram ->
// one global atomic per (block,bucket) reserves a contiguous chunk -> writes
// land in block-private chunks (coalesce/merge in L2).
__global__ __launch_bounds__(512) void bucketize_kernel(const int* __restrict__ ei,
                                                        int* __restrict__ curA,
                                                        int* __restrict__ curT,
                                                        int2* __restrict__ bktA,
                                                        int2* __restrict__ bktT) {
    __shared__ int cntA[NB], cntT[NB], baseA[NB], baseT[NB];
    const int tid = threadIdx.x;
    const int CH = (N_EDGES + gridDim.x - 1) / gridDim.x;
    const int e0 = blockIdx.x * CH;
    const int e1 = min(e0 + CH, N_EDGES);

    for (int i = tid; i < NB; i += 512) { cntA[i] = 0; cntT[i] = 0; }
    __syncthreads();
    for (int e = e0 + tid; e < e1; e += 512) {
        int r = ei[e];
        int c = ei[N_EDGES + e];
        atomicAdd(&cntA[r >> 8], 1);
        atomicAdd(&cntT[c >> 8], 1);
    }
    __syncthreads();
    for (int b = tid; b < NB; b += 512) {
        baseA[b] = cntA[b] ? atomicAdd(&curA[b], cntA[b]) : 0;
        baseT[b] = cntT[b] ? atomicAdd(&curT[b], cntT[b]) : 0;
        cntA[b] = 0;
        cntT[b] = 0;
    }
    __syncthreads();
    for (int e = e0 + tid; e < e1; e += 512) {
        int r = ei[e];
        int c = ei[N_EDGES + e];
        int pA = baseA[r >> 8] + atomicAdd(&cntA[r >> 8], 1);
        bktA[pA] = make_int2(r, c);
        int pT = baseT[c >> 8] + atomicAdd(&cntT[c >> 8], 1);
        bktT[pT] = make_int2(c, r);
    }
}

// ------------------------------------- phase 2: within-bucket counting scatter
// One block per (bucket, dir). Cursors in LDS; all writes land in this
// bucket's contiguous idx slice -> single-XCD, fully merged writebacks.
__global__ __launch_bounds__(512) void bucket_scatter_kernel(
        const int* __restrict__ rowptr, const int* __restrict__ colptr,
        const int2* __restrict__ bktA, const int2* __restrict__ bktT,
        int* __restrict__ idxA, int* __restrict__ idxT) {
    __shared__ int cur[BW];
    const int b = blockIdx.x;
    const int dirT = blockIdx.y;
    const int* ptr = dirT ? colptr : rowptr;
    const int2* bkt = dirT ? bktT : bktA;
    int* idx = dirT ? idxT : idxA;
    const int node0 = b * BW;
    const int tid = threadIdx.x;

    const int startb = ptr[node0];
    const int endb = (node0 + BW < N_NODES) ? ptr[node0 + BW] : N_EDGES;
    if (tid < BW) {
        int n = node0 + tid;
        cur[tid] = (n < N_NODES) ? ptr[n] : 0;
    }
    __syncthreads();
    for (int i = startb + tid; i < endb; i += 512) {
        int2 rec = bkt[i];
        int p = atomicAdd(&cur[rec.x - node0], 1);
        idx[p] = rec.y;
    }
}

// -------------------------------------------------------------- fused layer
__device__ __forceinline__ void fma4(float4& a, float w, const float4& f) {
    a.x = fmaf(w, f.x, a.x); a.y = fmaf(w, f.y, a.y);
    a.z = fmaf(w, f.z, a.z); a.w = fmaf(w, f.w, a.w);
}

__device__ __forceinline__ float4 red_s(float4 v) {
    v.x += __shfl_xor(v.x, 16); v.y += __shfl_xor(v.y, 16);
    v.z += __shfl_xor(v.z, 16); v.w += __shfl_xor(v.w, 16);
    v.x += __shfl_xor(v.x, 32); v.y += __shfl_xor(v.y, 32);
    v.z += __shfl_xor(v.z, 32); v.w += __shfl_xor(v.w, 32);
    return v;
}

// per-wave aggregation over one direction; lane (q,s): q=feat quad, s=edge slot
// rw[] = per-neighbor scale (r_in for dir A, r_out for dir T)
__device__ __forceinline__ float4 agg_dir(const float4* __restrict__ hv,
                                          const int* __restrict__ idx,
                                          const float* __restrict__ rw,
                                          int start, int deg, int q, int s) {
    float4 a0 = {0.f,0.f,0.f,0.f}, a1 = {0.f,0.f,0.f,0.f};
    int k = 0;
    for (; k + 8 <= deg; k += 8) {
        int c0 = idx[start + k + s];
        int c1 = idx[start + k + 4 + s];
        float w0 = rw[c0];
        float w1 = rw[c1];
        float4 f0 = hv[(size_t)c0 * 16 + q];
        float4 f1 = hv[(size_t)c1 * 16 + q];
        fma4(a0, w0, f0);
        fma4(a1, w1, f1);
    }
    if (k + s < deg) {
        int c0 = idx[start + k + s];
        float4 f0 = hv[(size_t)c0 * 16 + q];
        fma4(a0, rw[c0], f0);
    }
    if (k + 4 + s < deg) {
        int c1 = idx[start + k + 4 + s];
        float4 f1 = hv[(size_t)c1 * 16 + q];
        fma4(a1, rw[c1], f1);
    }
    a0.x += a1.x; a0.y += a1.y; a0.z += a1.z; a0.w += a1.w;
    return red_s(a0);
}

__global__ __launch_bounds__(512, 8) void layer_kernel(
        const float* __restrict__ h_in, float* __restrict__ h_out,
        const int* __restrict__ rowptr, const int* __restrict__ deg_out,
        const int* __restrict__ idxA,
        const int* __restrict__ colptr, const int* __restrict__ deg_in,
        const int* __restrict__ idxT,
        const float* __restrict__ r_out, const float* __restrict__ r_in,
        const float* __restrict__ ws, const float* __restrict__ bs,
        const float* __restrict__ wd, const float* __restrict__ bd) {
    __shared__ float4 s_ws[HDIM * 16];                 // [k][q] 16KB
    __shared__ float4 s_wd[HDIM * 16];                 // 16KB
    __shared__ float4 s_accv[BLK_NODES][2][16];        // 4KB

    const int tid  = threadIdx.x;
    const int wave = tid >> 6;
    const int lane = tid & 63;
    const int q = lane & 15;
    const int s = lane >> 4;
    const int node = blockIdx.x * BLK_NODES + wave;

    // stage weights (1024 float4 each; 512 threads x 2)
    const float4* wsv = (const float4*)ws;
    const float4* wdv = (const float4*)wd;
    s_ws[tid] = wsv[tid]; s_ws[tid + 512] = wsv[tid + 512];
    s_wd[tid] = wdv[tid]; s_wd[tid + 512] = wdv[tid + 512];

    const float4* hv = (const float4*)h_in;

    // dir A: r_out[node] * sum_{c in out-nbrs} r_in[c] * h[c]
    float scaleA = r_out[node];
    float4 aA = agg_dir(hv, idxA, r_in, rowptr[node], deg_out[node], q, s);
    if (s == 0) {
        aA.x *= scaleA; aA.y *= scaleA; aA.z *= scaleA; aA.w *= scaleA;
        s_accv[wave][0][q] = aA;
    }
    // dir T: r_in[node] * sum_{r in in-nbrs} r_out[r] * h[r]
    float scaleT = r_in[node];
    float4 aT = agg_dir(hv, idxT, r_out, colptr[node], deg_in[node], q, s);
    if (s == 0) {
        aT.x *= scaleT; aT.y *= scaleT; aT.z *= scaleT; aT.w *= scaleT;
        s_accv[wave][1][q] = aT;
    }

    __syncthreads();

    // GEMM epilogue: thread -> feats 4q..4q+3 of its node, k in [16s, 16s+16)
    const float* accA = (const float*)&s_accv[wave][0][0];
    const float* accT = (const float*)&s_accv[wave][1][0];
    float4 oA = {0.f,0.f,0.f,0.f}, oT = {0.f,0.f,0.f,0.f};
    const int k0 = s * 16;
#pragma unroll
    for (int i = 0; i < 16; i++) {
        int k = k0 + i;
        float vA = accA[k];
        float vT = accT[k];
        float4 wA = s_ws[k * 16 + q];
        float4 wT = s_wd[k * 16 + q];
        fma4(oA, vA, wA);
        fma4(oT, vT, wT);
    }
    float4 o;
    o.x = ALPHA_C * oA.x + BETA_C * oT.x;
    o.y = ALPHA_C * oA.y + BETA_C * oT.y;
    o.z = ALPHA_C * oA.z + BETA_C * oT.z;
    o.w = ALPHA_C * oA.w + BETA_C * oT.w;
    o = red_s(o);
    if (s == 0) {
        float4 bA = ((const float4*)bs)[q];
        float4 bD = ((const float4*)bd)[q];
        o.x = fmaxf(o.x + ALPHA_C * bA.x + BETA_C * bD.x, 0.0f);
        o.y = fmaxf(o.y + ALPHA_C * bA.y + BETA_C * bD.y, 0.0f);
        o.z = fmaxf(o.z + ALPHA_C * bA.z + BETA_C * bD.z, 0.0f);
        o.w = fmaxf(o.w + ALPHA_C * bA.w + BETA_C * bD.w, 0.0f);
        ((float4*)h_out)[(size_t)node * 16 + q] = o;
    }
}

// ---------------------------------------------------------------- max pool
__global__ __launch_bounds__(256) void pool_kernel(const float* __restrict__ h,
                                                   const int* __restrict__ batch,
                                                   unsigned* __restrict__ g) {
    int t = blockIdx.x * 256 + threadIdx.x;
    const int ngroups = N_NODES / 16;   // 6250
    if (t >= ngroups * 64) return;
    int f = t & 63;
    int n0 = (t >> 6) * 16;
    int curg = batch[n0];
    float m = 0.0f;                      // post-ReLU values are >= 0
    for (int n = n0; n < n0 + 16; n++) {
        int b = batch[n];
        if (b != curg) {
            atomicMax(&g[curg * HDIM + f], __float_as_uint(m));
            curg = b;
            m = 0.0f;
        }
        m = fmaxf(m, h[n * HDIM + f]);
    }
    atomicMax(&g[curg * HDIM + f], __float_as_uint(m));
}

// -------------------------------------------------------------------- MLP head
__global__ __launch_bounds__(64) void mlp_kernel(const unsigned* __restrict__ g,
                                                 const float* __restrict__ wl1,
                                                 const float* __restrict__ bl1,
                                                 const float* __restrict__ wl2,
                                                 const float* __restrict__ bl2,
                                                 float* __restrict__ out) {
    int t = threadIdx.x;   // graph index, one block of 64
    float gv[HDIM];
#pragma unroll
    for (int k = 0; k < HDIM; k++) gv[k] = __uint_as_float(g[t * HDIM + k]);
    float o = bl2[0];
#pragma unroll
    for (int j = 0; j < 5; j++) {
        float hj = bl1[j];
#pragma unroll
        for (int k = 0; k < HDIM; k++) hj += gv[k] * wl1[k * 5 + j];
        hj = fmaxf(hj, 0.0f);
        o += hj * wl2[j];
    }
    out[t] = o;
}

// ------------------------------------------------------------------- launch
extern "C" void kernel_launch(void* const* d_in, const int* in_sizes, int n_in,
                              void* d_out, int out_size, void* d_ws, size_t ws_size,
                              hipStream_t stream) {
    const float* x   = (const float*)d_in[0];
    const int*   ei  = (const int*)d_in[1];
    const int*   bat = (const int*)d_in[2];
    const float* w1s = (const float*)d_in[3];
    const float* b1s = (const float*)d_in[4];
    const float* w1d = (const float*)d_in[5];
    const float* b1d = (const float*)d_in[6];
    const float* w2s = (const float*)d_in[7];
    const float* b2s = (const float*)d_in[8];
    const float* w2d = (const float*)d_in[9];
    const float* b2d = (const float*)d_in[10];
    const float* w3s = (const float*)d_in[11];
    const float* b3s = (const float*)d_in[12];
    const float* w3d = (const float*)d_in[13];
    const float* b3d = (const float*)d_in[14];
    const float* wl1 = (const float*)d_in[15];
    const float* bl1 = (const float*)d_in[16];
    const float* wl2 = (const float*)d_in[17];
    const float* bl2 = (const float*)d_in[18];
    float* out = (float*)d_out;

    // Workspace carve-up (all chunks 16B-aligned). bktA/bktT alias hA: they
    // are dead before the first layer_kernel writes hA.
    char* p = (char*)d_ws;
    int*   deg_out = (int*)p;              p += N_NODES * 4;
    int*   deg_in  = (int*)p;              p += N_NODES * 4;
    int*   rowptr  = (int*)p;              p += N_NODES * 4;
    int*   colptr  = (int*)p;              p += N_NODES * 4;
    float* r_out   = (float*)p;            p += N_NODES * 4;
    float* r_in    = (float*)p;            p += N_NODES * 4;
    int*   curA    = (int*)p;              p += 512 * 4;
    int*   curT    = (int*)p;              p += 512 * 4;
    int*   idxA    = (int*)p;              p += (size_t)N_EDGES * 4;
    int*   idxT    = (int*)p;              p += (size_t)N_EDGES * 4;
    int2*  bktA    = (int2*)p;             // aliased with hA
    float* hA      = (float*)p;            p += (size_t)N_EDGES * 8;
    int2*  bktT    = (int2*)(p - (size_t)N_EDGES * 8 + (size_t)N_EDGES * 8);
    // (bktA occupies first 12.8MB, bktT second 12.8MB, hA spans both 25.6MB)
    bktT = (int2*)((char*)bktA + (size_t)N_EDGES * 8);
    p = (char*)bktA + 2 * (size_t)N_EDGES * 8;
    float* hB      = (float*)p;            p += (size_t)N_NODES * HDIM * 4;
    unsigned* g    = (unsigned*)p;         p += NGRAPH * HDIM * 4;
    int*   bsum0   = (int*)p;              p += 512;
    int*   bsum1   = (int*)p;              p += 512;

    const int nb = (N_NODES + 1023) / 1024;   // 98 scan blocks

    hipMemsetAsync(deg_out, 0, 2 * N_NODES * 4, stream);
    hipMemsetAsync(g, 0, NGRAPH * HDIM * 4, stream);

    hist_kernel<<<(N_EDGES + 255) / 256, 256, 0, stream>>>(ei, deg_out, deg_in);
    rsq_kernel<<<(N_NODES + 255) / 256, 256, 0, stream>>>(deg_out, deg_in, r_out, r_in);

    dim3 gs(nb, 2);
    scan_block<<<gs, 1024, 0, stream>>>(deg_out, deg_in, rowptr, colptr, bsum0, bsum1);
    scan_bsums<<<2, 128, 0, stream>>>(bsum0, bsum1, nb);
    dim3 ga((N_NODES + 255) / 256, 2);
    scan_add<<<ga, 256, 0, stream>>>(rowptr, colptr, bsum0, bsum1);

    init_cursors<<<1, 512, 0, stream>>>(rowptr, colptr, curA, curT);
    bucketize_kernel<<<256, 512, 0, stream>>>(ei, curA, curT, bktA, bktT);
    dim3 gb(NB, 2);
    bucket_scatter_kernel<<<gb, 512, 0, stream>>>(rowptr, colptr, bktA, bktT, idxA, idxT);

    // Three fused conv layers: x -> hA -> hB -> hA
    layer_kernel<<<N_NODES / BLK_NODES, 512, 0, stream>>>(
        x, hA, rowptr, deg_out, idxA, colptr, deg_in, idxT, r_out, r_in,
        w1s, b1s, w1d, b1d);
    layer_kernel<<<N_NODES / BLK_NODES, 512, 0, stream>>>(
        hA, hB, rowptr, deg_out, idxA, colptr, deg_in, idxT, r_out, r_in,
        w2s, b2s, w2d, b2d);
    layer_kernel<<<N_NODES / BLK_NODES, 512, 0, stream>>>(
        hB, hA, rowptr, deg_out, idxA, colptr, deg_in, idxT, r_out, r_in,
        w3s, b3s, w3d, b3d);

    const int pool_threads = (N_NODES / 16) * 64;   // 400000
    pool_kernel<<<(pool_threads + 255) / 256, 256, 0, stream>>>(hA, bat, g);

    mlp_kernel<<<1, 64, 0, stream>>>(g, wl1, bl1, wl2, bl2, out);
}